// Round 12
// baseline (114.201 us; speedup 1.0000x reference)
//
#include <hip/hip_runtime.h>

// Problem constants
#define NROWS 8192   // 4 * 2048
#define DIM   512
#define NT    64                    // 8192 / 128 tiles per side
#define NTRI  (NT * (NT + 1) / 2)   // 2080 upper-triangular tile blocks
#define NACC  64                    // accumulator slots (contention spread)

using f32x4 = __attribute__((ext_vector_type(4))) float;

typedef __attribute__((address_space(1))) const void* as1_cvptr;
typedef __attribute__((address_space(3))) void*       as3_vptr;

// async global->LDS DMA, 16B per lane; LDS dest = wave-uniform base + lane*16
__device__ __forceinline__ void async16(const void* g, void* l) {
    __builtin_amdgcn_global_load_lds((as1_cvptr)g, (as3_vptr)l, 16, 0, 0);
}

// Software fp32 -> OCP e4m3fn, round-to-nearest-even (r7-r10-verified).
__device__ __forceinline__ unsigned char f2e4m3(float x) {
    unsigned ux = __float_as_uint(x);
    unsigned s  = (ux >> 24) & 0x80u;
    float a = __uint_as_float(ux & 0x7FFFFFFFu);     // |x|, finite for our data
    a = fminf(a, 448.0f);                            // clamp to max finite
    unsigned ua = __float_as_uint(a);
    int eb = (int)(ua >> 23);                        // biased exponent
    if (eb < 121) eb = 121;                          // denormal region: step 2^-9
    float step  = __uint_as_float((unsigned)(eb - 3) << 23);    // 2^(eb-130)
    float istep = __uint_as_float((unsigned)(257 - eb) << 23);  // 2^(130-eb), exact
    float q = rintf(a * istep) * step;               // RNE on e4m3 grid
    q = fminf(q, 448.0f);
    if (q < 0.001953125f)                            // below min denormal 2^-9 -> 0
        return (unsigned char)s;
    unsigned uq = __float_as_uint(q);
    int eq = (int)(uq >> 23) - 127;
    unsigned byte;
    if (eq < -6) byte = (unsigned)(q * 512.0f);      // denormal: d*2^-9, d in 1..7
    else         byte = (unsigned)((eq + 7) << 3) | ((uq >> 20) & 7u);
    return (unsigned char)(s | byte);
}

// Kernel 1: fp32 row norms + fp32->fp8 conversion into a pre-swizzled global
// layout for 256B K-half panels: row r = two 256B halves; within a half,
// 8B chunk cs (0..31) is stored at position cs ^ (r&15). GEMM frag reads
// then hit bank-pair cs^fr: 16 distinct per quarter-wave, 2-way across
// q-pairs (free, m136). One wave per row; a lane's 8 elems = one 8B chunk
// (half = lane>>5, chunk = lane&31).
__global__ __launch_bounds__(256) void norm_convert_kernel(
    const float* __restrict__ X, unsigned char* __restrict__ Xq,
    float* __restrict__ norms, float* __restrict__ acc)
{
    const int tid  = threadIdx.x;
    const int lane = tid & 63;
    const int w    = tid >> 6;
    const int row  = blockIdx.x * 4 + w;

    if (blockIdx.x == 0 && tid < NACC) acc[tid] = 0.0f;

    const float* xr = X + (size_t)row * DIM + lane * 8;
    float4 v0 = *(const float4*)xr;
    float4 v1 = *(const float4*)(xr + 4);

    float s = 0.0f;
    s = fmaf(v0.x, v0.x, s); s = fmaf(v0.y, v0.y, s);
    s = fmaf(v0.z, v0.z, s); s = fmaf(v0.w, v0.w, s);
    s = fmaf(v1.x, v1.x, s); s = fmaf(v1.y, v1.y, s);
    s = fmaf(v1.z, v1.z, s); s = fmaf(v1.w, v1.w, s);

    union { unsigned char b[8]; uint2 v; } pk;
    pk.b[0] = f2e4m3(v0.x); pk.b[1] = f2e4m3(v0.y);
    pk.b[2] = f2e4m3(v0.z); pk.b[3] = f2e4m3(v0.w);
    pk.b[4] = f2e4m3(v1.x); pk.b[5] = f2e4m3(v1.y);
    pk.b[6] = f2e4m3(v1.z); pk.b[7] = f2e4m3(v1.w);

    const int h    = lane >> 5;                         // 256B half
    const int cs   = lane & 31;                         // 8B chunk in half
    const int cpos = cs ^ (row & 15);                   // swizzled position
    *(uint2*)(Xq + (size_t)row * DIM + h * 256 + cpos * 8) = pk.v;

    #pragma unroll
    for (int off = 32; off > 0; off >>= 1) s += __shfl_down(s, off, 64);
    if (lane == 0) norms[row] = s;
}

// Kernel 2: upper-triangular tiled X·X^T (fp8 e4m3 MFMA) + fused sqrt/exp/sum
// epilogue. 128x128 tile/block, 4 waves, 64x64 quadrant/wave.
//
// K-HALF-RESIDENT structure (r11 lesson: tweaking vmcnt/lookahead on a
// barrier-per-iteration K-loop only trades occupancy for nothing; the fix
// is removing the per-iteration barrier entirely): LDS holds a full K=256
// half-panel of A and B (32KB each, 64KB/block, 2 blocks/CU). Whole kernel
// has 3 barriers: fill(h0) / sync / 8 uninterrupted k-steps / sync /
// fill(h1) / sync / 8 k-steps. No DMA is in flight during compute, so
// there is nothing to drain mid-loop; the two fill latencies per block are
// hidden CU-level by the co-resident block computing. (Differs from m132's
// failed BK=128: that kept per-iter barriers and paid the occupancy cost
// without removing them.)
// Frag read: row rl at rl*256; chunk s*4+q read at position (s*4+q)^fr ->
// bank-pair cs^fr, conflict-free per 16-lane phase, 2-way across q-pairs.
// DMA fills are linear 1KB-per-instr copies (conflict-free by construction).
// NO device-scope fences (r3: agent fence = per-XCD L2 flush, +40us).
__global__ __launch_bounds__(256, 2) void pair_loss_gemm_kernel(
    const unsigned char* __restrict__ Xq, const float* __restrict__ norms,
    float* __restrict__ acc)
{
    __shared__ __align__(16) char As[32768];
    __shared__ __align__(16) char Bs[32768];
    __shared__ float wsum[4];

    // decode linear block id -> upper-triangular (bi, bj), bi <= bj
    int t = blockIdx.x, bi = 0;
    while (t >= (NT - bi)) { t -= (NT - bi); bi++; }
    const int bj = bi + t;

    const int tid  = threadIdx.x;
    const int lane = tid & 63;
    const int w    = tid >> 6;

    const int rowA = bi * 128;
    const int rowB = bj * 128;

    f32x4 accv[4][4];
    const f32x4 zero = {0.0f, 0.0f, 0.0f, 0.0f};
    #pragma unroll
    for (int a = 0; a < 4; a++)
        #pragma unroll
        for (int b = 0; b < 4; b++) accv[a][b] = zero;

    // DMA fill addressing: half-panel = 128 rows x 256B = 2048 chunks of 16B.
    // Instr (w,n): LDS base As + (w*8+n)*1024; lane l covers LDS chunk
    // (w*8+n)*64 + l = row 4*(w*8+n)+(l>>4), piece l&15 -> global byte
    // row*512 + h*256 + piece*16 (linear copy of the swizzled 256B row).
    const int rl = lane >> 4;            // row offset within 4-row instr group
    const int pc = lane & 15;            // 16B piece within 256B row
    const unsigned char* gA = Xq + (size_t)(rowA + rl) * DIM + pc * 16;
    const unsigned char* gB = Xq + (size_t)(rowB + rl) * DIM + pc * 16;

    // MFMA fp8 frag: lane holds A[m=fr][k=q*8..q*8+7] per k-step, q=lane>>4.
    const int fr = lane & 15;
    const int q  = lane >> 4;
    const int wr = (w & 1) * 64;
    const int wc = (w >> 1) * 64;

    #pragma unroll 1
    for (int h = 0; h < 2; h++) {
        // fill half-panel h (8 DMA instrs per matrix per wave)
        #pragma unroll
        for (int n = 0; n < 8; n++) {
            const int go = h * 256 + (w * 8 + n) * 2048;   // global byte offset
            const int lo = (w * 8 + n) * 1024;             // LDS byte offset
            async16(gA + go, As + lo);
            async16(gB + go, Bs + lo);
        }
        __syncthreads();   // drains DMA (vmcnt), publishes panels

        // 8 uninterrupted k-steps over the resident K=256 panel
        #pragma unroll
        for (int s = 0; s < 8; s++) {
            const int off = (((s * 4 + q) ^ fr) & 31) * 8;
            long af[4], bf[4];
            #pragma unroll
            for (int a = 0; a < 4; a++)
                af[a] = *(const long*)(As + (wr + a * 16 + fr) * 256 + off);
            #pragma unroll
            for (int b = 0; b < 4; b++)
                bf[b] = *(const long*)(Bs + (wc + b * 16 + fr) * 256 + off);
            #pragma unroll
            for (int a = 0; a < 4; a++)
                #pragma unroll
                for (int b = 0; b < 4; b++)
                    accv[a][b] = __builtin_amdgcn_mfma_f32_16x16x32_fp8_fp8(
                        af[a], bf[b], accv[a][b], 0, 0, 0);
        }
        if (h == 0) __syncthreads();   // retire reads before overwrite
    }

    // epilogue: term = exp(-0.1*sqrt(max(ni+nj-2*dot, 0))); diag -> 1
    // C/D layout: col = lane&15, row = (lane>>4)*4 + reg (dtype-independent)
    const float wgt = (bi == bj) ? 1.0f : 2.0f;
    float lsum = 0.0f;
    #pragma unroll
    for (int a = 0; a < 4; a++) {
        const int gi0 = rowA + wr + a * 16 + (lane >> 4) * 4;
        #pragma unroll
        for (int b = 0; b < 4; b++) {
            const int gj = rowB + wc + b * 16 + (lane & 15);
            const float nj = norms[gj];
            #pragma unroll
            for (int r = 0; r < 4; r++) {
                const int gi = gi0 + r;
                float sq = fmaf(-2.0f, accv[a][b][r], norms[gi] + nj);
                sq = fmaxf(sq, 0.0f);
                float term = __expf(-0.1f * sqrtf(sq));
                if (gi == gj) term = 1.0f;
                lsum += term;
            }
        }
    }
    lsum *= wgt;
    #pragma unroll
    for (int off = 32; off > 0; off >>= 1) lsum += __shfl_down(lsum, off, 64);
    if (lane == 0) wsum[w] = lsum;
    __syncthreads();
    if (tid == 0)
        atomicAdd(&acc[blockIdx.x & (NACC - 1)],
                  wsum[0] + wsum[1] + wsum[2] + wsum[3]);
}

// Kernel 3: finalize scalar outputs (sum NACC slots)
__global__ void finalize_kernel(const float* __restrict__ acc,
                                float* __restrict__ out)
{
    const int lane = threadIdx.x;
    float s = (lane < NACC) ? acc[lane] : 0.0f;
    #pragma unroll
    for (int off = 32; off > 0; off >>= 1) s += __shfl_down(s, off, 64);
    if (lane == 0) {
        const float inv = 1.0f / ((float)NROWS * (float)NROWS); // 2^-26 exact
        float loss = s * inv * 0.1f;
        out[0] = loss;
        out[1] = 0.5f * loss;
    }
}

extern "C" void kernel_launch(void* const* d_in, const int* in_sizes, int n_in,
                              void* d_out, int out_size, void* d_ws, size_t ws_size,
                              hipStream_t stream)
{
    const float* X = (const float*)d_in[0];
    float* out = (float*)d_out;

    char* ws = (char*)d_ws;
    float*         acc   = (float*)ws;                   // NACC fp32 slots
    float*         norms = (float*)(ws + 1024);          // 8192 fp32 (32 KB)
    unsigned char* Xq    = (unsigned char*)(ws + 1024 + 32768); // fp8 X, 4 MB

    norm_convert_kernel<<<NROWS / 4, 256, 0, stream>>>(X, Xq, norms, acc);
    pair_loss_gemm_kernel<<<NTRI, 256, 0, stream>>>(Xq, norms, acc);
    finalize_kernel<<<1, 64, 0, stream>>>(acc, out);
}

// Round 13
// 111.366 us; speedup vs baseline: 1.0255x; 1.0255x over previous
//
#include <hip/hip_runtime.h>

// Problem constants
#define NROWS 8192   // 4 * 2048
#define DIM   512
#define NT    64                    // 8192 / 128 tiles per side
#define NTRI  (NT * (NT + 1) / 2)   // 2080 upper-triangular tile blocks
#define NACC  64                    // accumulator slots (contention spread)

using f32x4 = __attribute__((ext_vector_type(4))) float;
using i32x8 = __attribute__((ext_vector_type(8))) int;

typedef __attribute__((address_space(1))) const void* as1_cvptr;
typedef __attribute__((address_space(3))) void*       as3_vptr;

// async global->LDS DMA, 16B per lane; LDS dest = wave-uniform base + lane*16
__device__ __forceinline__ void async16(const void* g, void* l) {
    __builtin_amdgcn_global_load_lds((as1_cvptr)g, (as3_vptr)l, 16, 0, 0);
}

// Software fp32 -> OCP e4m3fn, round-to-nearest-even (r7-r12-verified).
__device__ __forceinline__ unsigned char f2e4m3(float x) {
    unsigned ux = __float_as_uint(x);
    unsigned s  = (ux >> 24) & 0x80u;
    float a = __uint_as_float(ux & 0x7FFFFFFFu);     // |x|, finite for our data
    a = fminf(a, 448.0f);                            // clamp to max finite
    unsigned ua = __float_as_uint(a);
    int eb = (int)(ua >> 23);                        // biased exponent
    if (eb < 121) eb = 121;                          // denormal region: step 2^-9
    float step  = __uint_as_float((unsigned)(eb - 3) << 23);    // 2^(eb-130)
    float istep = __uint_as_float((unsigned)(257 - eb) << 23);  // 2^(130-eb), exact
    float q = rintf(a * istep) * step;               // RNE on e4m3 grid
    q = fminf(q, 448.0f);
    if (q < 0.001953125f)                            // below min denormal 2^-9 -> 0
        return (unsigned char)s;
    unsigned uq = __float_as_uint(q);
    int eq = (int)(uq >> 23) - 127;
    unsigned byte;
    if (eq < -6) byte = (unsigned)(q * 512.0f);      // denormal: d*2^-9, d in 1..7
    else         byte = (unsigned)((eq + 7) << 3) | ((uq >> 20) & 7u);
    return (unsigned char)(s | byte);
}

// Kernel 1: fp32 row norms + fp32->fp8 conversion into a pre-swizzled global
// layout for BK=128 tiles: row r = four 128B k-groups; within a group, 16B
// piece p is stored at position p ^ (r&7). GEMM staging is then a straight
// linear DMA copy and frag b128 reads are <=2-way in LDS (free, m136).
// One wave per row; a lane's 8 elems = one 8B half-piece
// (group = lane>>4, piece = (lane&15)>>1, half = lane&1).
__global__ __launch_bounds__(256) void norm_convert_kernel(
    const float* __restrict__ X, unsigned char* __restrict__ Xq,
    float* __restrict__ norms, float* __restrict__ acc)
{
    const int tid  = threadIdx.x;
    const int lane = tid & 63;
    const int w    = tid >> 6;
    const int row  = blockIdx.x * 4 + w;

    if (blockIdx.x == 0 && tid < NACC) acc[tid] = 0.0f;

    const float* xr = X + (size_t)row * DIM + lane * 8;
    float4 v0 = *(const float4*)xr;
    float4 v1 = *(const float4*)(xr + 4);

    float s = 0.0f;
    s = fmaf(v0.x, v0.x, s); s = fmaf(v0.y, v0.y, s);
    s = fmaf(v0.z, v0.z, s); s = fmaf(v0.w, v0.w, s);
    s = fmaf(v1.x, v1.x, s); s = fmaf(v1.y, v1.y, s);
    s = fmaf(v1.z, v1.z, s); s = fmaf(v1.w, v1.w, s);

    union { unsigned char b[8]; uint2 v; } pk;
    pk.b[0] = f2e4m3(v0.x); pk.b[1] = f2e4m3(v0.y);
    pk.b[2] = f2e4m3(v0.z); pk.b[3] = f2e4m3(v0.w);
    pk.b[4] = f2e4m3(v1.x); pk.b[5] = f2e4m3(v1.y);
    pk.b[6] = f2e4m3(v1.z); pk.b[7] = f2e4m3(v1.w);

    const int g    = lane >> 4;                        // 128B k-group
    const int p    = (lane & 15) >> 1;                 // 16B piece in group
    const int h    = lane & 1;                         // 8B half
    const int ppos = p ^ (row & 7);                    // swizzled position
    *(uint2*)(Xq + (size_t)row * DIM + g * 128 + ppos * 16 + h * 8) = pk.v;

    #pragma unroll
    for (int off = 32; off > 0; off >>= 1) s += __shfl_down(s, off, 64);
    if (lane == 0) norms[row] = s;
}

// Kernel 2: upper-triangular tiled X·X^T via MX-scaled fp8 MFMA
// (mfma_scale_f32_16x16x128_f8f6f4, unit e8m0 scales = bit-identical to the
// r10-verified non-scaled fp8 math, but 2x rate and K=128/instr) + fused
// sqrt/exp/sum epilogue. 128x128 tile/block, 4 waves, 64x64 quadrant/wave,
// BK=128: 4 iterations, 16 MFMA/iter, 8 DMA instr/iter/wave, 4 barriers
// total (r10 had 8; r12 showed barrier-free-but-low-occupancy loses).
//
// LDS: 2 buffers x (16KB A + 16KB B) = 64KB -> 2 blocks/CU. Frags+acc live
// in regs: 64 frag + 64 acc + addr ~ 145 < 256 at (256,2): no spill.
// Frag read: lane (fr=lane&15, q=lane>>4) holds k=q*32..q*32+31 -> two
// b128 reads at row*128 + ((2q)^...)*16 / ((2q+1)^...)*16; pre-swizzle
// makes every quarter-phase <=2-way (free). DMA writes linear.
// NO device-scope fences (r3) / no raw-asm barriers (r11 regression).
__global__ __launch_bounds__(256, 2) void pair_loss_gemm_kernel(
    const unsigned char* __restrict__ Xq, const float* __restrict__ norms,
    float* __restrict__ acc)
{
    __shared__ __align__(16) char As[2][16384];
    __shared__ __align__(16) char Bs[2][16384];
    __shared__ float wsum[4];

    // decode linear block id -> upper-triangular (bi, bj), bi <= bj
    int t = blockIdx.x, bi = 0;
    while (t >= (NT - bi)) { t -= (NT - bi); bi++; }
    const int bj = bi + t;

    const int tid  = threadIdx.x;
    const int lane = tid & 63;
    const int w    = tid >> 6;

    const int rowA = bi * 128;
    const int rowB = bj * 128;

    f32x4 accv[4][4];
    const f32x4 zero = {0.0f, 0.0f, 0.0f, 0.0f};
    #pragma unroll
    for (int a = 0; a < 4; a++)
        #pragma unroll
        for (int b = 0; b < 4; b++) accv[a][b] = zero;

    // DMA staging: per iter, tile = 128 rows x 128B = 1024 chunks of 16B per
    // matrix. Wave w, instr n (0..3): chunks w*256+n*64+lane -> row
    // w*32+n*8+(lane>>3), piece-pos lane&7 (linear copy of swizzled global).
    const unsigned char* gA =
        Xq + (size_t)(rowA + w * 32 + (lane >> 3)) * DIM + (lane & 7) * 16;
    const unsigned char* gB =
        Xq + (size_t)(rowB + w * 32 + (lane >> 3)) * DIM + (lane & 7) * 16;
    const int ldw = w * 4096;            // wave-uniform LDS base within tile

    // MFMA frag addressing: lane (fr,q); k-piece 2q (+1) of row fr sits at
    // swizzled position (2q)^(fr&7) ((2q+1)^(fr&7)).
    const int fr  = lane & 15;
    const int q   = lane >> 4;
    const int foL = ((2 * q)     ^ (fr & 7)) * 16;
    const int foH = ((2 * q + 1) ^ (fr & 7)) * 16;
    const int wr  = (w & 1) * 64;
    const int wc  = (w >> 1) * 64;

    // prologue: DMA k-group 0 into buffer 0
    #pragma unroll
    for (int n = 0; n < 4; n++) {
        async16(gA + n * 4096, As[0] + ldw + n * 1024);
        async16(gB + n * 4096, Bs[0] + ldw + n * 1024);
    }
    __syncthreads();

    #pragma unroll 1
    for (int g = 0; g < 4; g++) {
        const int cur = g & 1;
        const char* curA = As[cur];
        const char* curB = Bs[cur];

        // frag reads: 16 x ds_read_b128 assembled into v8i32 fragments
        union { uint4 h[2]; i32x8 v; } af[4], bf[4];
        #pragma unroll
        for (int a = 0; a < 4; a++) {
            const char* rb = curA + (wr + a * 16 + fr) * 128;
            af[a].h[0] = *(const uint4*)(rb + foL);
            af[a].h[1] = *(const uint4*)(rb + foH);
        }
        #pragma unroll
        for (int b = 0; b < 4; b++) {
            const char* rb = curB + (wc + b * 16 + fr) * 128;
            bf[b].h[0] = *(const uint4*)(rb + foL);
            bf[b].h[1] = *(const uint4*)(rb + foH);
        }

        // DMA next k-group into the other buffer; lands during the MFMAs
        const bool more = (g < 3);
        if (more) {
            const int nxt = cur ^ 1;
            const int go  = (g + 1) * 128;
            #pragma unroll
            for (int n = 0; n < 4; n++) {
                async16(gA + go + n * 4096, As[nxt] + ldw + n * 1024);
                async16(gB + go + n * 4096, Bs[nxt] + ldw + n * 1024);
            }
        }

        // 16 MX MFMAs, K=128, A/B fmt fp8-e4m3 (cbsz=blgp=0), unit scales
        // (e8m0 0x7F = 2^0) -> bit-identical to non-scaled fp8 at 2x rate.
        #pragma unroll
        for (int a = 0; a < 4; a++)
            #pragma unroll
            for (int b = 0; b < 4; b++)
                accv[a][b] = __builtin_amdgcn_mfma_scale_f32_16x16x128_f8f6f4(
                    af[a].v, bf[b].v, accv[a][b], 0, 0,
                    0, 0x7F7F7F7F, 0, 0x7F7F7F7F);

        if (more) __syncthreads();   // drains DMA, publishes next buffer
    }

    // epilogue: term = exp(-0.1*sqrt(max(ni+nj-2*dot, 0))); diag -> 1
    // C/D layout: col = lane&15, row = (lane>>4)*4 + reg (shape-determined)
    const float wgt = (bi == bj) ? 1.0f : 2.0f;
    float lsum = 0.0f;
    #pragma unroll
    for (int a = 0; a < 4; a++) {
        const int gi0 = rowA + wr + a * 16 + (lane >> 4) * 4;
        #pragma unroll
        for (int b = 0; b < 4; b++) {
            const int gj = rowB + wc + b * 16 + (lane & 15);
            const float nj = norms[gj];
            #pragma unroll
            for (int r = 0; r < 4; r++) {
                const int gi = gi0 + r;
                float sq = fmaf(-2.0f, accv[a][b][r], norms[gi] + nj);
                sq = fmaxf(sq, 0.0f);
                float term = __expf(-0.1f * sqrtf(sq));
                if (gi == gj) term = 1.0f;
                lsum += term;
            }
        }
    }
    lsum *= wgt;
    #pragma unroll
    for (int off = 32; off > 0; off >>= 1) lsum += __shfl_down(lsum, off, 64);
    if (lane == 0) wsum[w] = lsum;
    __syncthreads();
    if (tid == 0)
        atomicAdd(&acc[blockIdx.x & (NACC - 1)],
                  wsum[0] + wsum[1] + wsum[2] + wsum[3]);
}

// Kernel 3: finalize scalar outputs (sum NACC slots)
__global__ void finalize_kernel(const float* __restrict__ acc,
                                float* __restrict__ out)
{
    const int lane = threadIdx.x;
    float s = (lane < NACC) ? acc[lane] : 0.0f;
    #pragma unroll
    for (int off = 32; off > 0; off >>= 1) s += __shfl_down(s, off, 64);
    if (lane == 0) {
        const float inv = 1.0f / ((float)NROWS * (float)NROWS); // 2^-26 exact
        float loss = s * inv * 0.1f;
        out[0] = loss;
        out[1] = 0.5f * loss;
    }
}

extern "C" void kernel_launch(void* const* d_in, const int* in_sizes, int n_in,
                              void* d_out, int out_size, void* d_ws, size_t ws_size,
                              hipStream_t stream)
{
    const float* X = (const float*)d_in[0];
    float* out = (float*)d_out;

    char* ws = (char*)d_ws;
    float*         acc   = (float*)ws;                   // NACC fp32 slots
    float*         norms = (float*)(ws + 1024);          // 8192 fp32 (32 KB)
    unsigned char* Xq    = (unsigned char*)(ws + 1024 + 32768); // fp8 X, 4 MB

    norm_convert_kernel<<<NROWS / 4, 256, 0, stream>>>(X, Xq, norms, acc);
    pair_loss_gemm_kernel<<<NTRI, 256, 0, stream>>>(Xq, norms, acc);
    finalize_kernel<<<1, 64, 0, stream>>>(acc, out);
}